// Round 1
// baseline (7857.951 us; speedup 1.0000x reference)
//
#include <hip/hip_runtime.h>
#include <hip/hip_bf16.h>

typedef unsigned short u16;
typedef short bf16x8 __attribute__((ext_vector_type(8)));
typedef float f32x4 __attribute__((ext_vector_type(4)));

__device__ __forceinline__ float ldbf(const u16* p) {
    __hip_bfloat16 h = *(const __hip_bfloat16*)p;
    return __bfloat162float(h);
}
__device__ __forceinline__ void stbf(u16* p, float f) {
    *(__hip_bfloat16*)p = __float2bfloat16(f);
}
__device__ __forceinline__ float bf2f(u16 v) {
    union { unsigned u; float f; } x; x.u = ((unsigned)v) << 16; return x.f;
}
__device__ __forceinline__ float sigm(float x) {
    return 1.0f / (1.0f + __expf(-x));
}

// ---------------------------------------------------------------------------
// f32 -> bf16 conversion (for w_hh)
// ---------------------------------------------------------------------------
__global__ __launch_bounds__(256) void cvt_bf16(const float* __restrict__ in,
                                                u16* __restrict__ out, int n) {
    int i = blockIdx.x * 256 + threadIdx.x;
    if (i < n) stbf(out + i, in[i]);
}

// ---------------------------------------------------------------------------
// Upsample conv (unchanged)
// ---------------------------------------------------------------------------
template <bool INF32>
__global__ __launch_bounds__(256) void upsample(const void* __restrict__ in_,
                                                const float* __restrict__ w,
                                                const float* __restrict__ bias_,
                                                u16* __restrict__ out,
                                                int Lin, int shift) {
    const int Cin = 1024 >> shift;
    const int total = 2 * Lin * 128 * 512;
    int idx = blockIdx.x * 256 + threadIdx.x;
    if (idx >= total) return;
    const int c  = idx & 511;
    const int bb = (idx >> 9) & 127;
    const int tp = idx >> 16;          // t = 2l + s
    const int s  = tp & 1;
    const int l  = tp >> 1;
    const int oc = c + (s << 9);
    const int ch = oc >> shift;
    float acc = bias_[oc];
    #pragma unroll
    for (int k = 0; k < 7; ++k) {
        int li = l + k - 3;
        if (li >= 0 && li < Lin) {
            size_t off = ((size_t)li * 128 + bb) * Cin + ch;
            float v = INF32 ? ((const float*)in_)[off] : ldbf((const u16*)in_ + off);
            acc += w[oc * 7 + k] * v;
        }
    }
    stbf(out + idx, fmaxf(acc, 0.0f));
}

// ---------------------------------------------------------------------------
// gates_x GEMM (MFMA). Output layout changed to [t][jt(32)][b(128)][g(4)][jr(16)]
// so each LSTM block's per-step gx slice is one contiguous 4 KB chunk.
// ---------------------------------------------------------------------------
__global__ __launch_bounds__(256) void gemm_gates(const float* __restrict__ x,
                                                  const u16* __restrict__ z2,
                                                  const float* __restrict__ wih,
                                                  const float* __restrict__ bih,
                                                  const float* __restrict__ bhh,
                                                  u16* __restrict__ gates) {
    __shared__ __align__(16) u16 smA[128 * 32];
    __shared__ __align__(16) u16 smB[128 * 32];
    const int tid  = threadIdx.x;
    const int lane = tid & 63;
    const int wave = tid >> 6;
    const int wm = wave >> 1, wn = wave & 1;
    const size_t mbase = (size_t)blockIdx.x * 128;
    const size_t nbase = (size_t)blockIdx.y * 128;

    f32x4 acc[4][4] = {};

    const int srow = tid >> 1;            // staging row 0..127
    const int scol = (tid & 1) * 16;      // staging col 0 or 16

    for (int kt = 0; kt < 32; ++kt) {
        const int kb = kt * 32;
        // stage A tile [128][32]
        if (kb < 512) {
            const float* src = x + (mbase + srow) * 512 + kb + scol;
            alignas(16) u16 tmp[16];
            #pragma unroll
            for (int q = 0; q < 16; ++q) stbf(&tmp[q], src[q]);
            *(int4*)&smA[srow * 32 + scol]     = *(const int4*)&tmp[0];
            *(int4*)&smA[srow * 32 + scol + 8] = *(const int4*)&tmp[8];
        } else {
            const u16* src = z2 + 65536 + (mbase + srow) * 512 + (kb - 512) + scol;
            *(int4*)&smA[srow * 32 + scol]     = *(const int4*)(src);
            *(int4*)&smA[srow * 32 + scol + 8] = *(const int4*)(src + 8);
        }
        // stage B tile [128][32] from f32 w_ih [2048][1024]
        {
            const float* src = wih + (nbase + srow) * 1024 + kb + scol;
            alignas(16) u16 tmp[16];
            #pragma unroll
            for (int q = 0; q < 16; ++q) stbf(&tmp[q], src[q]);
            *(int4*)&smB[srow * 32 + scol]     = *(const int4*)&tmp[0];
            *(int4*)&smB[srow * 32 + scol + 8] = *(const int4*)&tmp[8];
        }
        __syncthreads();

        bf16x8 af[4], bfr[4];
        #pragma unroll
        for (int mi = 0; mi < 4; ++mi)
            af[mi] = *(const bf16x8*)&smA[(wm * 64 + mi * 16 + (lane & 15)) * 32 + (lane >> 4) * 8];
        #pragma unroll
        for (int ni = 0; ni < 4; ++ni)
            bfr[ni] = *(const bf16x8*)&smB[(wn * 64 + ni * 16 + (lane & 15)) * 32 + (lane >> 4) * 8];
        #pragma unroll
        for (int mi = 0; mi < 4; ++mi)
            #pragma unroll
            for (int ni = 0; ni < 4; ++ni)
                acc[mi][ni] = __builtin_amdgcn_mfma_f32_16x16x32_bf16(af[mi], bfr[ni], acc[mi][ni], 0, 0, 0);
        __syncthreads();
    }

    // epilogue: C/D layout col = lane&15, row = (lane>>4)*4 + r
    // write to gates[t][jh>>4][b][g][jh&15]; t == blockIdx.x (mbase = t*128)
    u16* gt = gates + (size_t)blockIdx.x * 262144;
    #pragma unroll
    for (int ni = 0; ni < 4; ++ni) {
        const int n = (int)nbase + wn * 64 + ni * 16 + (lane & 15);
        const float bias = bih[n] + bhh[n];
        const int g  = n >> 9;
        const int jh = n & 511;
        u16* gb = gt + (size_t)(jh >> 4) * 8192 + (size_t)(g * 16 + (jh & 15));
        #pragma unroll
        for (int mi = 0; mi < 4; ++mi) {
            const int b = wm * 64 + mi * 16 + (lane >> 4) * 4;
            #pragma unroll
            for (int r = 0; r < 4; ++r)
                stbf(gb + (size_t)(b + r) * 64, acc[mi][ni][r] + bias);
        }
    }
}

// ---------------------------------------------------------------------------
// Persistent LSTM: whole 511-step recurrence in ONE kernel.
// Grid 128 blocks x 256 thr. Block bid: grp = bid>>5 (batch group of 32),
// jt = bid&31 (16-wide hidden-col tile). Groups are independent (LSTM is
// batch-parallel); each group syncs its 32 blocks with a spin barrier.
// w_hh slice (64x512 bf16 = 64 KB) lives in LDS for all steps (XOR-swizzled,
// G4: stride-1024B rows are 16-way bank conflicts otherwise). c-state lives
// in registers. Per step: stage h tile (32 KB, swizzled), 32 MFMA/wave,
// elementwise, write h slice, group barrier.
// ---------------------------------------------------------------------------
__global__ __launch_bounds__(256) void lstm_persist(const u16* __restrict__ gates,
                                                    const u16* __restrict__ whh,
                                                    u16* __restrict__ hbuf,
                                                    float* __restrict__ out,
                                                    unsigned* __restrict__ bar) {
    __shared__ __align__(16) u16 smW[32768];   // [64 n][512 k] swizzled (64 KB)
    __shared__ __align__(16) u16 smH[16384];   // [32 b][512 k] swizzled (32 KB)
    __shared__ __align__(16) float smG[2048];  // [4 g][32 b][16 j]

    const int tid  = threadIdx.x;
    const int lane = tid & 63;
    const int wave = tid >> 6;                 // gate group i,f,g,o
    const int bid  = blockIdx.x;
    const int grp  = bid >> 5;                 // batch group
    const int jt   = bid & 31;                 // hidden-col tile
    const int b0   = grp << 5;
    const int jh0  = jt << 4;

    // ---- stage w_hh slice once: row r -> whh[(r>>4)*512 + jh0 + (r&15)][*] ----
    for (int i = tid; i < 4096; i += 256) {
        const int row = i >> 6;                // 0..63
        const int c8  = i & 63;                // 16B chunk within row
        const u16* src = whh + ((size_t)((row >> 4) * 512 + jh0 + (row & 15))) * 512 + c8 * 8;
        int4 v = *(const int4*)src;
        int byte = row * 1024 + c8 * 16;
        byte ^= (row & 7) << 4;
        *(int4*)((char*)smW + byte) = v;
    }

    const int fr = lane & 15;                  // fragment row-in-tile
    const int kq = lane >> 4;                  // k quad
    const int br0 = tid >> 4;                  // elementwise batch row 0..15
    const int jr  = tid & 15;
    float c0 = 0.0f, c1 = 0.0f;                // c-state in registers

    __syncthreads();

    for (int t = 0; t < 511; ++t) {
        // ---- stage h tile [32][512] bf16, swizzled ----
        const u16* hsrc = hbuf + (size_t)(t & 1) * 65536 + (size_t)b0 * 512;
        #pragma unroll
        for (int rnd = 0; rnd < 8; ++rnd) {
            const int e   = rnd * 256 + tid;
            const int row = e >> 6;            // 0..31
            const int c8  = e & 63;
            int4 v = *(const int4*)(hsrc + row * 512 + c8 * 8);
            int byte = row * 1024 + c8 * 16;
            byte ^= (row & 7) << 4;
            *(int4*)((char*)smH + byte) = v;
        }
        // ---- prefetch gx (independent of h; hides under MFMA) ----
        const u16* gsrc = gates + (size_t)t * 262144 + (size_t)jt * 8192 + (size_t)b0 * 64;
        u16 gxu[2][4];
        #pragma unroll
        for (int u = 0; u < 2; ++u)
            #pragma unroll
            for (int g = 0; g < 4; ++g)
                gxu[u][g] = gsrc[((br0 + u * 16) * 4 + g) * 16 + jr];

        __syncthreads();

        // ---- gates GEMM: wave g computes [32 b][16 j] of gate g, K=512 ----
        f32x4 acc0 = {}, acc1 = {};
        const int brow = wave * 16 + fr;
        const int bxor = (brow & 7) << 4;
        const int axor = (fr & 7) << 4;
        #pragma unroll
        for (int kt = 0; kt < 16; ++kt) {
            const int kb = kt * 64 + kq * 16;
            bf16x8 bf = *(const bf16x8*)((const char*)smW + ((brow * 1024 + kb) ^ bxor));
            bf16x8 a0 = *(const bf16x8*)((const char*)smH + ((fr * 1024 + kb) ^ axor));
            bf16x8 a1 = *(const bf16x8*)((const char*)smH + (((16 + fr) * 1024 + kb) ^ axor));
            acc0 = __builtin_amdgcn_mfma_f32_16x16x32_bf16(a0, bf, acc0, 0, 0, 0);
            acc1 = __builtin_amdgcn_mfma_f32_16x16x32_bf16(a1, bf, acc1, 0, 0, 0);
        }

        // ---- dump gates to LDS: m = kq*4+r, n = fr ----
        #pragma unroll
        for (int r = 0; r < 4; ++r) {
            smG[(wave * 32 + kq * 4 + r) * 16 + fr]      = acc0[r];
            smG[(wave * 32 + 16 + kq * 4 + r) * 16 + fr] = acc1[r];
        }
        __syncthreads();

        // ---- elementwise LSTM: thread owns (br0,jr) and (br0+16,jr) ----
        u16*   hdst = hbuf + (size_t)((t + 1) & 1) * 65536;
        float* odst = out + ((size_t)t * 128 + b0) * 512 + jh0;
        #pragma unroll
        for (int u = 0; u < 2; ++u) {
            const int brr = br0 + u * 16;
            const float gi = smG[(0 * 32 + brr) * 16 + jr] + bf2f(gxu[u][0]);
            const float gf = smG[(1 * 32 + brr) * 16 + jr] + bf2f(gxu[u][1]);
            const float gg = smG[(2 * 32 + brr) * 16 + jr] + bf2f(gxu[u][2]);
            const float go = smG[(3 * 32 + brr) * 16 + jr] + bf2f(gxu[u][3]);
            float& c = u ? c1 : c0;
            c = sigm(gf) * c + sigm(gi) * tanhf(gg);
            const float hn = sigm(go) * tanhf(c);
            stbf(hdst + (size_t)(b0 + brr) * 512 + jh0 + jr, hn);
            odst[(size_t)brr * 512 + jr] = hn;
        }

        // ---- per-group barrier (release h, acquire others' h) ----
        if (t < 510) {
            __syncthreads();                   // drains vmcnt for whole block
            if (tid == 0) {
                __threadfence();               // release to device scope
                atomicAdd(&bar[grp], 1u);
                const unsigned tgt = (unsigned)(t + 1) * 32u;
                while (__hip_atomic_load(&bar[grp], __ATOMIC_RELAXED,
                                         __HIP_MEMORY_SCOPE_AGENT) < tgt)
                    __builtin_amdgcn_s_sleep(1);
                __threadfence();               // acquire
            }
            __syncthreads();
        }
    }
}

// ---------------------------------------------------------------------------
extern "C" void kernel_launch(void* const* d_in, const int* in_sizes, int n_in,
                              void* d_out, int out_size, void* d_ws, size_t ws_size,
                              hipStream_t stream) {
    const float* x   = (const float*)d_in[0];
    const float* z   = (const float*)d_in[1];
    const float* c0w = (const float*)d_in[2];
    const float* c0b = (const float*)d_in[3];
    const float* c1w = (const float*)d_in[4];
    const float* c1b = (const float*)d_in[5];
    const float* wih = (const float*)d_in[6];
    const float* whh = (const float*)d_in[7];
    const float* bih = (const float*)d_in[8];
    const float* bhh = (const float*)d_in[9];
    float* out = (float*)d_out;                // f32 output (reference dtype)
    char* ws = (char*)d_ws;

    // workspace layout (bytes) — total 371,195,904 (unchanged)
    u16*      z1     = (u16*)(ws);              //  33,554,432 B: [256][128][512] bf16
    u16*      z2     = (u16*)(ws + 33554432);   //  67,108,864 B: [512][128][512] bf16
    u16*      gates  = (u16*)(ws + 100663296);  // 267,911,168 B: [511][32][128][4][16] bf16
    unsigned* bar    = (unsigned*)(ws + 368574464); // barrier counters (4 used)
    u16*      hbuf   = (u16*)(ws + 368836608);  //     262,144 B: [2][128][512] bf16
    u16*      whh_bf = (u16*)(ws + 369098752);  //   2,097,152 B: [2048][512] bf16

    hipMemsetAsync(bar, 0, 256, stream);
    hipMemsetAsync(hbuf, 0, 131072, stream);    // zero h[0] buffer only

    // convert w_hh to bf16
    cvt_bf16<<<dim3(4096), 256, 0, stream>>>(whh, whh_bf, 1048576);

    // upsample x2
    upsample<true ><<<dim3(16777216 / 256), 256, 0, stream>>>(z,  c0w, c0b, z1, 128, 2);
    upsample<false><<<dim3(33554432 / 256), 256, 0, stream>>>(z1, c1w, c1b, z2, 256, 1);

    // gates_x = [x[:-1] | z2[1:]] @ w_ih^T + b_ih + b_hh  (new tiled layout)
    gemm_gates<<<dim3(511, 16), 256, 0, stream>>>(x, z2, wih, bih, bhh, gates);

    // whole recurrence in one cooperative persistent kernel
    {
        const u16* gates_a = gates;
        const u16* whh_a   = whh_bf;
        u16*       hbuf_a  = hbuf;
        float*     out_a   = out;
        unsigned*  bar_a   = bar;
        void* args[] = {&gates_a, &whh_a, &hbuf_a, &out_a, &bar_a};
        hipLaunchCooperativeKernel((void*)lstm_persist, dim3(128), dim3(256),
                                   args, 0, stream);
    }
}

// Round 2
// 5799.969 us; speedup vs baseline: 1.3548x; 1.3548x over previous
//
#include <hip/hip_runtime.h>
#include <hip/hip_bf16.h>

typedef unsigned short u16;
typedef unsigned long long u64;
typedef short bf16x8 __attribute__((ext_vector_type(8)));
typedef float f32x4 __attribute__((ext_vector_type(4)));

__device__ __forceinline__ float ldbf(const u16* p) {
    __hip_bfloat16 h = *(const __hip_bfloat16*)p;
    return __bfloat162float(h);
}
__device__ __forceinline__ void stbf(u16* p, float f) {
    *(__hip_bfloat16*)p = __float2bfloat16(f);
}
__device__ __forceinline__ u16 f2bfu(float f) {
    __hip_bfloat16 h = __float2bfloat16(f);
    return *(u16*)&h;
}
__device__ __forceinline__ float bf2f(u16 v) {
    union { unsigned u; float f; } x; x.u = ((unsigned)v) << 16; return x.f;
}
__device__ __forceinline__ float sigm(float x) {
    return 1.0f / (1.0f + __expf(-x));
}

// ---------------------------------------------------------------------------
// f32 -> bf16 conversion (for w_hh)
// ---------------------------------------------------------------------------
__global__ __launch_bounds__(256) void cvt_bf16(const float* __restrict__ in,
                                                u16* __restrict__ out, int n) {
    int i = blockIdx.x * 256 + threadIdx.x;
    if (i < n) stbf(out + i, in[i]);
}

// ---------------------------------------------------------------------------
// Upsample conv (unchanged)
// ---------------------------------------------------------------------------
template <bool INF32>
__global__ __launch_bounds__(256) void upsample(const void* __restrict__ in_,
                                                const float* __restrict__ w,
                                                const float* __restrict__ bias_,
                                                u16* __restrict__ out,
                                                int Lin, int shift) {
    const int Cin = 1024 >> shift;
    const int total = 2 * Lin * 128 * 512;
    int idx = blockIdx.x * 256 + threadIdx.x;
    if (idx >= total) return;
    const int c  = idx & 511;
    const int bb = (idx >> 9) & 127;
    const int tp = idx >> 16;          // t = 2l + s
    const int s  = tp & 1;
    const int l  = tp >> 1;
    const int oc = c + (s << 9);
    const int ch = oc >> shift;
    float acc = bias_[oc];
    #pragma unroll
    for (int k = 0; k < 7; ++k) {
        int li = l + k - 3;
        if (li >= 0 && li < Lin) {
            size_t off = ((size_t)li * 128 + bb) * Cin + ch;
            float v = INF32 ? ((const float*)in_)[off] : ldbf((const u16*)in_ + off);
            acc += w[oc * 7 + k] * v;
        }
    }
    stbf(out + idx, fmaxf(acc, 0.0f));
}

// ---------------------------------------------------------------------------
// gates_x GEMM (MFMA). Output layout [t][jt(32)][b(128)][g(4)][jr(16)] so each
// LSTM block's per-step gx slice is one contiguous 4 KB chunk. (unchanged)
// ---------------------------------------------------------------------------
__global__ __launch_bounds__(256) void gemm_gates(const float* __restrict__ x,
                                                  const u16* __restrict__ z2,
                                                  const float* __restrict__ wih,
                                                  const float* __restrict__ bih,
                                                  const float* __restrict__ bhh,
                                                  u16* __restrict__ gates) {
    __shared__ __align__(16) u16 smA[128 * 32];
    __shared__ __align__(16) u16 smB[128 * 32];
    const int tid  = threadIdx.x;
    const int lane = tid & 63;
    const int wave = tid >> 6;
    const int wm = wave >> 1, wn = wave & 1;
    const size_t mbase = (size_t)blockIdx.x * 128;
    const size_t nbase = (size_t)blockIdx.y * 128;

    f32x4 acc[4][4] = {};

    const int srow = tid >> 1;            // staging row 0..127
    const int scol = (tid & 1) * 16;      // staging col 0 or 16

    for (int kt = 0; kt < 32; ++kt) {
        const int kb = kt * 32;
        // stage A tile [128][32]
        if (kb < 512) {
            const float* src = x + (mbase + srow) * 512 + kb + scol;
            alignas(16) u16 tmp[16];
            #pragma unroll
            for (int q = 0; q < 16; ++q) stbf(&tmp[q], src[q]);
            *(int4*)&smA[srow * 32 + scol]     = *(const int4*)&tmp[0];
            *(int4*)&smA[srow * 32 + scol + 8] = *(const int4*)&tmp[8];
        } else {
            const u16* src = z2 + 65536 + (mbase + srow) * 512 + (kb - 512) + scol;
            *(int4*)&smA[srow * 32 + scol]     = *(const int4*)(src);
            *(int4*)&smA[srow * 32 + scol + 8] = *(const int4*)(src + 8);
        }
        // stage B tile [128][32] from f32 w_ih [2048][1024]
        {
            const float* src = wih + (nbase + srow) * 1024 + kb + scol;
            alignas(16) u16 tmp[16];
            #pragma unroll
            for (int q = 0; q < 16; ++q) stbf(&tmp[q], src[q]);
            *(int4*)&smB[srow * 32 + scol]     = *(const int4*)&tmp[0];
            *(int4*)&smB[srow * 32 + scol + 8] = *(const int4*)&tmp[8];
        }
        __syncthreads();

        bf16x8 af[4], bfr[4];
        #pragma unroll
        for (int mi = 0; mi < 4; ++mi)
            af[mi] = *(const bf16x8*)&smA[(wm * 64 + mi * 16 + (lane & 15)) * 32 + (lane >> 4) * 8];
        #pragma unroll
        for (int ni = 0; ni < 4; ++ni)
            bfr[ni] = *(const bf16x8*)&smB[(wn * 64 + ni * 16 + (lane & 15)) * 32 + (lane >> 4) * 8];
        #pragma unroll
        for (int mi = 0; mi < 4; ++mi)
            #pragma unroll
            for (int ni = 0; ni < 4; ++ni)
                acc[mi][ni] = __builtin_amdgcn_mfma_f32_16x16x32_bf16(af[mi], bfr[ni], acc[mi][ni], 0, 0, 0);
        __syncthreads();
    }

    // epilogue: C/D layout col = lane&15, row = (lane>>4)*4 + r
    u16* gt = gates + (size_t)blockIdx.x * 262144;
    #pragma unroll
    for (int ni = 0; ni < 4; ++ni) {
        const int n = (int)nbase + wn * 64 + ni * 16 + (lane & 15);
        const float bias = bih[n] + bhh[n];
        const int g  = n >> 9;
        const int jh = n & 511;
        u16* gb = gt + (size_t)(jh >> 4) * 8192 + (size_t)(g * 16 + (jh & 15));
        #pragma unroll
        for (int mi = 0; mi < 4; ++mi) {
            const int b = wm * 64 + mi * 16 + (lane >> 4) * 4;
            #pragma unroll
            for (int r = 0; r < 4; ++r)
                stbf(gb + (size_t)(b + r) * 64, acc[mi][ni][r] + bias);
        }
    }
}

// ---------------------------------------------------------------------------
// Persistent LSTM, round 2: NO fences in the loop.
// Cross-XCD h exchange goes through the coherence point explicitly:
//   - h stores: packed-u32 agent-scope RELAXED atomic stores (bypass local L2)
//   - h loads:  8-byte agent-scope RELAXED atomic loads (bypass stale L2)
//   - barrier:  relaxed atomic counter; ordering = s_waitcnt vmcnt(0) +
//               __syncthreads (all stores ack'd at coherence point before
//               the arrival add; flag observed before any h load issues).
// __threadfence (= buffer_wbl2/buffer_inv full-L2 flush per step, the round-1
// 12.9 us/step cost) is gone entirely.
// ---------------------------------------------------------------------------
__global__ __launch_bounds__(256) void lstm_persist(const u16* __restrict__ gates,
                                                    const u16* __restrict__ whh,
                                                    u16* __restrict__ hbuf,
                                                    float* __restrict__ out,
                                                    unsigned* __restrict__ bar) {
    __shared__ __align__(16) u16 smW[32768];   // [64 n][512 k] swizzled (64 KB)
    __shared__ __align__(16) u16 smH[16384];   // [32 b][512 k] swizzled (32 KB)
    __shared__ __align__(16) float smG[4 * 32 * 18];  // pad 16->18: kills kq conflict

    const int tid  = threadIdx.x;
    const int lane = tid & 63;
    const int wave = tid >> 6;                 // gate group i,f,g,o
    const int bid  = blockIdx.x;
    const int grp  = bid >> 5;                 // batch group
    const int jt   = bid & 31;                 // hidden-col tile
    const int b0   = grp << 5;
    const int jh0  = jt << 4;

    // ---- stage w_hh slice once (plain loads: written by an earlier kernel) ----
    for (int i = tid; i < 4096; i += 256) {
        const int row = i >> 6;                // 0..63
        const int c8  = i & 63;                // 16B chunk within row
        const u16* src = whh + ((size_t)((row >> 4) * 512 + jh0 + (row & 15))) * 512 + c8 * 8;
        int4 v = *(const int4*)src;
        int byte = row * 1024 + c8 * 16;
        byte ^= (row & 7) << 4;
        *(int4*)((char*)smW + byte) = v;
    }

    const int fr = lane & 15;                  // fragment row-in-tile
    const int kq = lane >> 4;                  // k quad
    const int br = tid >> 3;                   // elementwise batch row 0..31
    const int j2 = (tid & 7) * 2;              // elementwise col pair
    float cA = 0.0f, cB = 0.0f;                // c-state in registers (j2, j2+1)

    __syncthreads();

    for (int t = 0; t < 511; ++t) {
        // ---- stage h tile [32][512] bf16, swizzled, via coherent 8B loads ----
        const u64* hp = (const u64*)(hbuf + (size_t)(t & 1) * 65536 + (size_t)b0 * 512);
        #pragma unroll
        for (int i = 0; i < 16; ++i) {
            const int e   = i * 256 + tid;
            const int row = e >> 7;            // 0..31
            const int c4  = e & 127;           // 8B chunk within row
            u64 v = __hip_atomic_load(hp + row * 128 + c4,
                                      __ATOMIC_RELAXED, __HIP_MEMORY_SCOPE_AGENT);
            int byte = (row * 1024 + c4 * 8) ^ ((row & 7) << 4);
            *(u64*)((char*)smH + byte) = v;
        }
        // ---- prefetch gx (independent; hides under MFMA) ----
        const u16* gsrc = gates + (size_t)t * 262144 + (size_t)jt * 8192 + (size_t)b0 * 64;
        unsigned gx4[4];
        #pragma unroll
        for (int g = 0; g < 4; ++g)
            gx4[g] = *(const unsigned*)(gsrc + br * 64 + g * 16 + j2);

        __syncthreads();

        // ---- gates GEMM: wave g computes [32 b][16 j] of gate g, K=512 ----
        f32x4 acc0 = {}, acc1 = {};
        const int brow = wave * 16 + fr;
        const int bxor = (brow & 7) << 4;
        const int axor = (fr & 7) << 4;
        #pragma unroll
        for (int kt = 0; kt < 16; ++kt) {
            const int kb = kt * 64 + kq * 16;
            bf16x8 bf = *(const bf16x8*)((const char*)smW + ((brow * 1024 + kb) ^ bxor));
            bf16x8 a0 = *(const bf16x8*)((const char*)smH + ((fr * 1024 + kb) ^ axor));
            bf16x8 a1 = *(const bf16x8*)((const char*)smH + (((16 + fr) * 1024 + kb) ^ axor));
            acc0 = __builtin_amdgcn_mfma_f32_16x16x32_bf16(a0, bf, acc0, 0, 0, 0);
            acc1 = __builtin_amdgcn_mfma_f32_16x16x32_bf16(a1, bf, acc1, 0, 0, 0);
        }

        // ---- dump gates to LDS: m = kq*4+r, n = fr (row pad 18 floats) ----
        #pragma unroll
        for (int r = 0; r < 4; ++r) {
            smG[(wave * 32 + kq * 4 + r) * 18 + fr]      = acc0[r];
            smG[(wave * 32 + 16 + kq * 4 + r) * 18 + fr] = acc1[r];
        }
        __syncthreads();

        // ---- elementwise LSTM: thread owns (br, j2) and (br, j2+1) ----
        u16*   hdst = hbuf + (size_t)((t + 1) & 1) * 65536;
        float* odst = out + ((size_t)t * 128 + b0 + br) * 512 + jh0;
        float hn0, hn1;
        {
            const float gi = smG[(0 * 32 + br) * 18 + j2] + bf2f((u16)(gx4[0] & 0xffff));
            const float gf = smG[(1 * 32 + br) * 18 + j2] + bf2f((u16)(gx4[1] & 0xffff));
            const float gg = smG[(2 * 32 + br) * 18 + j2] + bf2f((u16)(gx4[2] & 0xffff));
            const float go = smG[(3 * 32 + br) * 18 + j2] + bf2f((u16)(gx4[3] & 0xffff));
            cA = sigm(gf) * cA + sigm(gi) * tanhf(gg);
            hn0 = sigm(go) * tanhf(cA);
        }
        {
            const float gi = smG[(0 * 32 + br) * 18 + j2 + 1] + bf2f((u16)(gx4[0] >> 16));
            const float gf = smG[(1 * 32 + br) * 18 + j2 + 1] + bf2f((u16)(gx4[1] >> 16));
            const float gg = smG[(2 * 32 + br) * 18 + j2 + 1] + bf2f((u16)(gx4[2] >> 16));
            const float go = smG[(3 * 32 + br) * 18 + j2 + 1] + bf2f((u16)(gx4[3] >> 16));
            cB = sigm(gf) * cB + sigm(gi) * tanhf(gg);
            hn1 = sigm(go) * tanhf(cB);
        }
        // h store: packed u32, coherent (bypasses local L2, lands at L3)
        {
            const unsigned hw = (unsigned)f2bfu(hn0) | ((unsigned)f2bfu(hn1) << 16);
            __hip_atomic_store((unsigned*)(hdst + (size_t)(b0 + br) * 512 + jh0 + j2),
                               hw, __ATOMIC_RELAXED, __HIP_MEMORY_SCOPE_AGENT);
        }
        // out store: plain cached f32 (visibility at kernel end)
        *(float2*)(odst + j2) = make_float2(hn0, hn1);

        // ---- per-group barrier: no fences, vmcnt-ordered relaxed atomics ----
        if (t < 510) {
            asm volatile("s_waitcnt vmcnt(0)" ::: "memory");  // own h stores ack'd
            __syncthreads();                                  // whole block ack'd
            if (tid == 0) {
                __hip_atomic_fetch_add(&bar[grp], 1u,
                                       __ATOMIC_RELAXED, __HIP_MEMORY_SCOPE_AGENT);
                const unsigned tgt = (unsigned)(t + 1) * 32u;
                while (__hip_atomic_load(&bar[grp], __ATOMIC_RELAXED,
                                         __HIP_MEMORY_SCOPE_AGENT) < tgt)
                    __builtin_amdgcn_s_sleep(2);
            }
            __syncthreads();
            asm volatile("" ::: "memory");
        }
    }
}

// ---------------------------------------------------------------------------
extern "C" void kernel_launch(void* const* d_in, const int* in_sizes, int n_in,
                              void* d_out, int out_size, void* d_ws, size_t ws_size,
                              hipStream_t stream) {
    const float* x   = (const float*)d_in[0];
    const float* z   = (const float*)d_in[1];
    const float* c0w = (const float*)d_in[2];
    const float* c0b = (const float*)d_in[3];
    const float* c1w = (const float*)d_in[4];
    const float* c1b = (const float*)d_in[5];
    const float* wih = (const float*)d_in[6];
    const float* whh = (const float*)d_in[7];
    const float* bih = (const float*)d_in[8];
    const float* bhh = (const float*)d_in[9];
    float* out = (float*)d_out;                // f32 output (reference dtype)
    char* ws = (char*)d_ws;

    // workspace layout (bytes) — total 371,195,904 (unchanged)
    u16*      z1     = (u16*)(ws);              //  33,554,432 B: [256][128][512] bf16
    u16*      z2     = (u16*)(ws + 33554432);   //  67,108,864 B: [512][128][512] bf16
    u16*      gates  = (u16*)(ws + 100663296);  // 267,911,168 B: [511][32][128][4][16] bf16
    unsigned* bar    = (unsigned*)(ws + 368574464); // barrier counters (4 used)
    u16*      hbuf   = (u16*)(ws + 368836608);  //     262,144 B: [2][128][512] bf16
    u16*      whh_bf = (u16*)(ws + 369098752);  //   2,097,152 B: [2048][512] bf16

    hipMemsetAsync(bar, 0, 256, stream);
    hipMemsetAsync(hbuf, 0, 131072, stream);    // zero h[0] buffer only

    // convert w_hh to bf16
    cvt_bf16<<<dim3(4096), 256, 0, stream>>>(whh, whh_bf, 1048576);

    // upsample x2
    upsample<true ><<<dim3(16777216 / 256), 256, 0, stream>>>(z,  c0w, c0b, z1, 128, 2);
    upsample<false><<<dim3(33554432 / 256), 256, 0, stream>>>(z1, c1w, c1b, z2, 256, 1);

    // gates_x = [x[:-1] | z2[1:]] @ w_ih^T + b_ih + b_hh  (tiled layout)
    gemm_gates<<<dim3(511, 16), 256, 0, stream>>>(x, z2, wih, bih, bhh, gates);

    // whole recurrence in one cooperative persistent kernel
    {
        const u16* gates_a = gates;
        const u16* whh_a   = whh_bf;
        u16*       hbuf_a  = hbuf;
        float*     out_a   = out;
        unsigned*  bar_a   = bar;
        void* args[] = {&gates_a, &whh_a, &hbuf_a, &out_a, &bar_a};
        hipLaunchCooperativeKernel((void*)lstm_persist, dim3(128), dim3(256),
                                   args, 0, stream);
    }
}

// Round 3
// 3349.277 us; speedup vs baseline: 2.3462x; 1.7317x over previous
//
#include <hip/hip_runtime.h>
#include <hip/hip_bf16.h>

typedef unsigned short u16;
typedef unsigned long long u64;
typedef short bf16x8 __attribute__((ext_vector_type(8)));
typedef float f32x4 __attribute__((ext_vector_type(4)));

__device__ __forceinline__ float ldbf(const u16* p) {
    __hip_bfloat16 h = *(const __hip_bfloat16*)p;
    return __bfloat162float(h);
}
__device__ __forceinline__ void stbf(u16* p, float f) {
    *(__hip_bfloat16*)p = __float2bfloat16(f);
}
__device__ __forceinline__ u16 f2bfu(float f) {
    __hip_bfloat16 h = __float2bfloat16(f);
    return *(u16*)&h;
}
__device__ __forceinline__ float bf2f(u16 v) {
    union { unsigned u; float f; } x; x.u = ((unsigned)v) << 16; return x.f;
}
__device__ __forceinline__ float sigm(float x) {
    return 1.0f / (1.0f + __expf(-x));
}

// ---------------------------------------------------------------------------
// f32 -> bf16 conversion (for w_hh)
// ---------------------------------------------------------------------------
__global__ __launch_bounds__(256) void cvt_bf16(const float* __restrict__ in,
                                                u16* __restrict__ out, int n) {
    int i = blockIdx.x * 256 + threadIdx.x;
    if (i < n) stbf(out + i, in[i]);
}

// ---------------------------------------------------------------------------
// Upsample conv (unchanged)
// ---------------------------------------------------------------------------
template <bool INF32>
__global__ __launch_bounds__(256) void upsample(const void* __restrict__ in_,
                                                const float* __restrict__ w,
                                                const float* __restrict__ bias_,
                                                u16* __restrict__ out,
                                                int Lin, int shift) {
    const int Cin = 1024 >> shift;
    const int total = 2 * Lin * 128 * 512;
    int idx = blockIdx.x * 256 + threadIdx.x;
    if (idx >= total) return;
    const int c  = idx & 511;
    const int bb = (idx >> 9) & 127;
    const int tp = idx >> 16;          // t = 2l + s
    const int s  = tp & 1;
    const int l  = tp >> 1;
    const int oc = c + (s << 9);
    const int ch = oc >> shift;
    float acc = bias_[oc];
    #pragma unroll
    for (int k = 0; k < 7; ++k) {
        int li = l + k - 3;
        if (li >= 0 && li < Lin) {
            size_t off = ((size_t)li * 128 + bb) * Cin + ch;
            float v = INF32 ? ((const float*)in_)[off] : ldbf((const u16*)in_ + off);
            acc += w[oc * 7 + k] * v;
        }
    }
    stbf(out + idx, fmaxf(acc, 0.0f));
}

// ---------------------------------------------------------------------------
// gates_x GEMM (MFMA). Output layout [t][jt(32)][b(128)][g(4)][jr(16)] so each
// LSTM block's per-step gx slice is one contiguous 4 KB chunk. (unchanged)
// ---------------------------------------------------------------------------
__global__ __launch_bounds__(256) void gemm_gates(const float* __restrict__ x,
                                                  const u16* __restrict__ z2,
                                                  const float* __restrict__ wih,
                                                  const float* __restrict__ bih,
                                                  const float* __restrict__ bhh,
                                                  u16* __restrict__ gates) {
    __shared__ __align__(16) u16 smA[128 * 32];
    __shared__ __align__(16) u16 smB[128 * 32];
    const int tid  = threadIdx.x;
    const int lane = tid & 63;
    const int wave = tid >> 6;
    const int wm = wave >> 1, wn = wave & 1;
    const size_t mbase = (size_t)blockIdx.x * 128;
    const size_t nbase = (size_t)blockIdx.y * 128;

    f32x4 acc[4][4] = {};

    const int srow = tid >> 1;            // staging row 0..127
    const int scol = (tid & 1) * 16;      // staging col 0 or 16

    for (int kt = 0; kt < 32; ++kt) {
        const int kb = kt * 32;
        // stage A tile [128][32]
        if (kb < 512) {
            const float* src = x + (mbase + srow) * 512 + kb + scol;
            alignas(16) u16 tmp[16];
            #pragma unroll
            for (int q = 0; q < 16; ++q) stbf(&tmp[q], src[q]);
            *(int4*)&smA[srow * 32 + scol]     = *(const int4*)&tmp[0];
            *(int4*)&smA[srow * 32 + scol + 8] = *(const int4*)&tmp[8];
        } else {
            const u16* src = z2 + 65536 + (mbase + srow) * 512 + (kb - 512) + scol;
            *(int4*)&smA[srow * 32 + scol]     = *(const int4*)(src);
            *(int4*)&smA[srow * 32 + scol + 8] = *(const int4*)(src + 8);
        }
        // stage B tile [128][32] from f32 w_ih [2048][1024]
        {
            const float* src = wih + (nbase + srow) * 1024 + kb + scol;
            alignas(16) u16 tmp[16];
            #pragma unroll
            for (int q = 0; q < 16; ++q) stbf(&tmp[q], src[q]);
            *(int4*)&smB[srow * 32 + scol]     = *(const int4*)&tmp[0];
            *(int4*)&smB[srow * 32 + scol + 8] = *(const int4*)&tmp[8];
        }
        __syncthreads();

        bf16x8 af[4], bfr[4];
        #pragma unroll
        for (int mi = 0; mi < 4; ++mi)
            af[mi] = *(const bf16x8*)&smA[(wm * 64 + mi * 16 + (lane & 15)) * 32 + (lane >> 4) * 8];
        #pragma unroll
        for (int ni = 0; ni < 4; ++ni)
            bfr[ni] = *(const bf16x8*)&smB[(wn * 64 + ni * 16 + (lane & 15)) * 32 + (lane >> 4) * 8];
        #pragma unroll
        for (int mi = 0; mi < 4; ++mi)
            #pragma unroll
            for (int ni = 0; ni < 4; ++ni)
                acc[mi][ni] = __builtin_amdgcn_mfma_f32_16x16x32_bf16(af[mi], bfr[ni], acc[mi][ni], 0, 0, 0);
        __syncthreads();
    }

    // epilogue: C/D layout col = lane&15, row = (lane>>4)*4 + r
    u16* gt = gates + (size_t)blockIdx.x * 262144;
    #pragma unroll
    for (int ni = 0; ni < 4; ++ni) {
        const int n = (int)nbase + wn * 64 + ni * 16 + (lane & 15);
        const float bias = bih[n] + bhh[n];
        const int g  = n >> 9;
        const int jh = n & 511;
        u16* gb = gt + (size_t)(jh >> 4) * 8192 + (size_t)(g * 16 + (jh & 15));
        #pragma unroll
        for (int mi = 0; mi < 4; ++mi) {
            const int b = wm * 64 + mi * 16 + (lane >> 4) * 4;
            #pragma unroll
            for (int r = 0; r < 4; ++r)
                stbf(gb + (size_t)(b + r) * 64, acc[mi][ni][r] + bias);
        }
    }
}

// ---------------------------------------------------------------------------
// Persistent LSTM, round 3.
// Round-2 bug: the h-staging loop interleaved each agent-scope atomic load
// with its LDS write, and atomics don't reorder past the ds_write -> the
// compiler emitted load; s_waitcnt vmcnt(0); ds_write SIXTEEN times =
// 16 serialized L3 round trips (~6 us/step, the whole regression vs theory).
// Fix: batch-issue all 16 loads into registers (no intermediate uses), then
// write LDS. Also pad the per-group barrier counters to 256 B apart (the 4
// counters shared one cacheline hammered by 128 blocks).
// ---------------------------------------------------------------------------
__global__ __launch_bounds__(256) void lstm_persist(const u16* __restrict__ gates,
                                                    const u16* __restrict__ whh,
                                                    u16* __restrict__ hbuf,
                                                    float* __restrict__ out,
                                                    unsigned* __restrict__ bar) {
    __shared__ __align__(16) u16 smW[32768];   // [64 n][512 k] swizzled (64 KB)
    __shared__ __align__(16) u16 smH[16384];   // [32 b][512 k] swizzled (32 KB)
    __shared__ __align__(16) float smG[4 * 32 * 18];  // pad 16->18: kills kq conflict

    const int tid  = threadIdx.x;
    const int lane = tid & 63;
    const int wave = tid >> 6;                 // gate group i,f,g,o
    const int bid  = blockIdx.x;
    const int grp  = bid >> 5;                 // batch group
    const int jt   = bid & 31;                 // hidden-col tile
    const int b0   = grp << 5;
    const int jh0  = jt << 4;
    unsigned* gbar = bar + grp * 64;           // 256 B apart: no false sharing

    // ---- stage w_hh slice once (plain loads: written by an earlier kernel) ----
    for (int i = tid; i < 4096; i += 256) {
        const int row = i >> 6;                // 0..63
        const int c8  = i & 63;                // 16B chunk within row
        const u16* src = whh + ((size_t)((row >> 4) * 512 + jh0 + (row & 15))) * 512 + c8 * 8;
        int4 v = *(const int4*)src;
        int byte = row * 1024 + c8 * 16;
        byte ^= (row & 7) << 4;
        *(int4*)((char*)smW + byte) = v;
    }

    const int fr = lane & 15;                  // fragment row-in-tile
    const int kq = lane >> 4;                  // k quad
    const int br = tid >> 3;                   // elementwise batch row 0..31
    const int j2 = (tid & 7) * 2;              // elementwise col pair
    float cA = 0.0f, cB = 0.0f;                // c-state in registers (j2, j2+1)

    __syncthreads();

    for (int t = 0; t < 511; ++t) {
        // ---- stage h tile [32][512] bf16: batch-issue 16 coherent loads ----
        const u64* hp = (const u64*)(hbuf + (size_t)(t & 1) * 65536 + (size_t)b0 * 512);
        u64 tmp[16];
        #pragma unroll
        for (int i = 0; i < 16; ++i)
            tmp[i] = __hip_atomic_load(hp + i * 256 + tid,
                                       __ATOMIC_RELAXED, __HIP_MEMORY_SCOPE_AGENT);
        __builtin_amdgcn_sched_barrier(0);     // keep LDS writes below the loads
        #pragma unroll
        for (int i = 0; i < 16; ++i) {
            const int e   = i * 256 + tid;
            const int row = e >> 7;            // 0..31
            const int c4  = e & 127;           // 8B chunk within row
            const int byte = (row * 1024 + c4 * 8) ^ ((row & 7) << 4);
            *(u64*)((char*)smH + byte) = tmp[i];
        }
        // ---- prefetch gx (independent; hides under MFMA) ----
        const u16* gsrc = gates + (size_t)t * 262144 + (size_t)jt * 8192 + (size_t)b0 * 64;
        unsigned gx4[4];
        #pragma unroll
        for (int g = 0; g < 4; ++g)
            gx4[g] = *(const unsigned*)(gsrc + br * 64 + g * 16 + j2);

        __syncthreads();

        // ---- gates GEMM: wave g computes [32 b][16 j] of gate g, K=512 ----
        f32x4 acc0 = {}, acc1 = {};
        const int brow = wave * 16 + fr;
        const int bxor = (brow & 7) << 4;
        const int axor = (fr & 7) << 4;
        #pragma unroll
        for (int kt = 0; kt < 16; ++kt) {
            const int kb = kt * 64 + kq * 16;
            bf16x8 bf = *(const bf16x8*)((const char*)smW + ((brow * 1024 + kb) ^ bxor));
            bf16x8 a0 = *(const bf16x8*)((const char*)smH + ((fr * 1024 + kb) ^ axor));
            bf16x8 a1 = *(const bf16x8*)((const char*)smH + (((16 + fr) * 1024 + kb) ^ axor));
            acc0 = __builtin_amdgcn_mfma_f32_16x16x32_bf16(a0, bf, acc0, 0, 0, 0);
            acc1 = __builtin_amdgcn_mfma_f32_16x16x32_bf16(a1, bf, acc1, 0, 0, 0);
        }

        // ---- dump gates to LDS: m = kq*4+r, n = fr (row pad 18 floats) ----
        #pragma unroll
        for (int r = 0; r < 4; ++r) {
            smG[(wave * 32 + kq * 4 + r) * 18 + fr]      = acc0[r];
            smG[(wave * 32 + 16 + kq * 4 + r) * 18 + fr] = acc1[r];
        }
        __syncthreads();

        // ---- elementwise LSTM: thread owns (br, j2) and (br, j2+1) ----
        u16*   hdst = hbuf + (size_t)((t + 1) & 1) * 65536;
        float* odst = out + ((size_t)t * 128 + b0 + br) * 512 + jh0;
        float hn0, hn1;
        {
            const float gi = smG[(0 * 32 + br) * 18 + j2] + bf2f((u16)(gx4[0] & 0xffff));
            const float gf = smG[(1 * 32 + br) * 18 + j2] + bf2f((u16)(gx4[1] & 0xffff));
            const float gg = smG[(2 * 32 + br) * 18 + j2] + bf2f((u16)(gx4[2] & 0xffff));
            const float go = smG[(3 * 32 + br) * 18 + j2] + bf2f((u16)(gx4[3] & 0xffff));
            cA = sigm(gf) * cA + sigm(gi) * tanhf(gg);
            hn0 = sigm(go) * tanhf(cA);
        }
        {
            const float gi = smG[(0 * 32 + br) * 18 + j2 + 1] + bf2f((u16)(gx4[0] >> 16));
            const float gf = smG[(1 * 32 + br) * 18 + j2 + 1] + bf2f((u16)(gx4[1] >> 16));
            const float gg = smG[(2 * 32 + br) * 18 + j2 + 1] + bf2f((u16)(gx4[2] >> 16));
            const float go = smG[(3 * 32 + br) * 18 + j2 + 1] + bf2f((u16)(gx4[3] >> 16));
            cB = sigm(gf) * cB + sigm(gi) * tanhf(gg);
            hn1 = sigm(go) * tanhf(cB);
        }
        // h store: packed u32, coherent (bypasses local L2, lands at L3)
        {
            const unsigned hw = (unsigned)f2bfu(hn0) | ((unsigned)f2bfu(hn1) << 16);
            __hip_atomic_store((unsigned*)(hdst + (size_t)(b0 + br) * 512 + jh0 + j2),
                               hw, __ATOMIC_RELAXED, __HIP_MEMORY_SCOPE_AGENT);
        }
        // out store: plain cached f32 (visibility at kernel end)
        *(float2*)(odst + j2) = make_float2(hn0, hn1);

        // ---- per-group barrier: no fences, vmcnt-ordered relaxed atomics ----
        if (t < 510) {
            asm volatile("s_waitcnt vmcnt(0)" ::: "memory");  // own h stores ack'd
            __syncthreads();                                  // whole block ack'd
            if (tid == 0) {
                __hip_atomic_fetch_add(gbar, 1u,
                                       __ATOMIC_RELAXED, __HIP_MEMORY_SCOPE_AGENT);
                const unsigned tgt = (unsigned)(t + 1) * 32u;
                while (__hip_atomic_load(gbar, __ATOMIC_RELAXED,
                                         __HIP_MEMORY_SCOPE_AGENT) < tgt)
                    __builtin_amdgcn_s_sleep(2);
            }
            __syncthreads();
            asm volatile("" ::: "memory");
        }
    }
}

// ---------------------------------------------------------------------------
extern "C" void kernel_launch(void* const* d_in, const int* in_sizes, int n_in,
                              void* d_out, int out_size, void* d_ws, size_t ws_size,
                              hipStream_t stream) {
    const float* x   = (const float*)d_in[0];
    const float* z   = (const float*)d_in[1];
    const float* c0w = (const float*)d_in[2];
    const float* c0b = (const float*)d_in[3];
    const float* c1w = (const float*)d_in[4];
    const float* c1b = (const float*)d_in[5];
    const float* wih = (const float*)d_in[6];
    const float* whh = (const float*)d_in[7];
    const float* bih = (const float*)d_in[8];
    const float* bhh = (const float*)d_in[9];
    float* out = (float*)d_out;                // f32 output (reference dtype)
    char* ws = (char*)d_ws;

    // workspace layout (bytes) — total 371,195,904 (unchanged)
    u16*      z1     = (u16*)(ws);              //  33,554,432 B: [256][128][512] bf16
    u16*      z2     = (u16*)(ws + 33554432);   //  67,108,864 B: [512][128][512] bf16
    u16*      gates  = (u16*)(ws + 100663296);  // 267,911,168 B: [511][32][128][4][16] bf16
    unsigned* bar    = (unsigned*)(ws + 368574464); // barrier counters, 256B apart
    u16*      hbuf   = (u16*)(ws + 368836608);  //     262,144 B: [2][128][512] bf16
    u16*      whh_bf = (u16*)(ws + 369098752);  //   2,097,152 B: [2048][512] bf16

    hipMemsetAsync(bar, 0, 1024, stream);
    hipMemsetAsync(hbuf, 0, 131072, stream);    // zero h[0] buffer only

    // convert w_hh to bf16
    cvt_bf16<<<dim3(4096), 256, 0, stream>>>(whh, whh_bf, 1048576);

    // upsample x2
    upsample<true ><<<dim3(16777216 / 256), 256, 0, stream>>>(z,  c0w, c0b, z1, 128, 2);
    upsample<false><<<dim3(33554432 / 256), 256, 0, stream>>>(z1, c1w, c1b, z2, 256, 1);

    // gates_x = [x[:-1] | z2[1:]] @ w_ih^T + b_ih + b_hh  (tiled layout)
    gemm_gates<<<dim3(511, 16), 256, 0, stream>>>(x, z2, wih, bih, bhh, gates);

    // whole recurrence in one cooperative persistent kernel
    {
        const u16* gates_a = gates;
        const u16* whh_a   = whh_bf;
        u16*       hbuf_a  = hbuf;
        float*     out_a   = out;
        unsigned*  bar_a   = bar;
        void* args[] = {&gates_a, &whh_a, &hbuf_a, &out_a, &bar_a};
        hipLaunchCooperativeKernel((void*)lstm_persist, dim3(128), dim3(256),
                                   args, 0, stream);
    }
}

// Round 5
// 3123.340 us; speedup vs baseline: 2.5159x; 1.0723x over previous
//
#include <hip/hip_runtime.h>
#include <hip/hip_bf16.h>

typedef unsigned short u16;
typedef unsigned long long u64;
typedef short bf16x8 __attribute__((ext_vector_type(8)));
typedef float f32x4 __attribute__((ext_vector_type(4)));

__device__ __forceinline__ float ldbf(const u16* p) {
    __hip_bfloat16 h = *(const __hip_bfloat16*)p;
    return __bfloat162float(h);
}
__device__ __forceinline__ void stbf(u16* p, float f) {
    *(__hip_bfloat16*)p = __float2bfloat16(f);
}
__device__ __forceinline__ u16 f2bfu(float f) {
    __hip_bfloat16 h = __float2bfloat16(f);
    return *(u16*)&h;
}
__device__ __forceinline__ float bf2f(u16 v) {
    union { unsigned u; float f; } x; x.u = ((unsigned)v) << 16; return x.f;
}
__device__ __forceinline__ float sigm(float x) {
    return 1.0f / (1.0f + __expf(-x));
}
// saturation-correct fast tanh: x>>0 -> e=inf -> 1; x<<0 -> e=0 -> -1
__device__ __forceinline__ float tanh_fast(float x) {
    float e = __expf(2.0f * x);
    return 1.0f - 2.0f / (e + 1.0f);
}

// ---------------------------------------------------------------------------
// f32 -> bf16 conversion (for w_hh)
// ---------------------------------------------------------------------------
__global__ __launch_bounds__(256) void cvt_bf16(const float* __restrict__ in,
                                                u16* __restrict__ out, int n) {
    int i = blockIdx.x * 256 + threadIdx.x;
    if (i < n) stbf(out + i, in[i]);
}

// ---------------------------------------------------------------------------
// Upsample conv (unchanged)
// ---------------------------------------------------------------------------
template <bool INF32>
__global__ __launch_bounds__(256) void upsample(const void* __restrict__ in_,
                                                const float* __restrict__ w,
                                                const float* __restrict__ bias_,
                                                u16* __restrict__ out,
                                                int Lin, int shift) {
    const int Cin = 1024 >> shift;
    const int total = 2 * Lin * 128 * 512;
    int idx = blockIdx.x * 256 + threadIdx.x;
    if (idx >= total) return;
    const int c  = idx & 511;
    const int bb = (idx >> 9) & 127;
    const int tp = idx >> 16;          // t = 2l + s
    const int s  = tp & 1;
    const int l  = tp >> 1;
    const int oc = c + (s << 9);
    const int ch = oc >> shift;
    float acc = bias_[oc];
    #pragma unroll
    for (int k = 0; k < 7; ++k) {
        int li = l + k - 3;
        if (li >= 0 && li < Lin) {
            size_t off = ((size_t)li * 128 + bb) * Cin + ch;
            float v = INF32 ? ((const float*)in_)[off] : ldbf((const u16*)in_ + off);
            acc += w[oc * 7 + k] * v;
        }
    }
    stbf(out + idx, fmaxf(acc, 0.0f));
}

// ---------------------------------------------------------------------------
// gates_x GEMM (MFMA). Output layout [t][jt(32)][b(128)][g(4)][jr(16)].
// (unchanged)
// ---------------------------------------------------------------------------
__global__ __launch_bounds__(256) void gemm_gates(const float* __restrict__ x,
                                                  const u16* __restrict__ z2,
                                                  const float* __restrict__ wih,
                                                  const float* __restrict__ bih,
                                                  const float* __restrict__ bhh,
                                                  u16* __restrict__ gates) {
    __shared__ __align__(16) u16 smA[128 * 32];
    __shared__ __align__(16) u16 smB[128 * 32];
    const int tid  = threadIdx.x;
    const int lane = tid & 63;
    const int wave = tid >> 6;
    const int wm = wave >> 1, wn = wave & 1;
    const size_t mbase = (size_t)blockIdx.x * 128;
    const size_t nbase = (size_t)blockIdx.y * 128;

    f32x4 acc[4][4] = {};

    const int srow = tid >> 1;            // staging row 0..127
    const int scol = (tid & 1) * 16;      // staging col 0 or 16

    for (int kt = 0; kt < 32; ++kt) {
        const int kb = kt * 32;
        // stage A tile [128][32]
        if (kb < 512) {
            const float* src = x + (mbase + srow) * 512 + kb + scol;
            alignas(16) u16 tmp[16];
            #pragma unroll
            for (int q = 0; q < 16; ++q) stbf(&tmp[q], src[q]);
            *(int4*)&smA[srow * 32 + scol]     = *(const int4*)&tmp[0];
            *(int4*)&smA[srow * 32 + scol + 8] = *(const int4*)&tmp[8];
        } else {
            const u16* src = z2 + 65536 + (mbase + srow) * 512 + (kb - 512) + scol;
            *(int4*)&smA[srow * 32 + scol]     = *(const int4*)(src);
            *(int4*)&smA[srow * 32 + scol + 8] = *(const int4*)(src + 8);
        }
        // stage B tile [128][32] from f32 w_ih [2048][1024]
        {
            const float* src = wih + (nbase + srow) * 1024 + kb + scol;
            alignas(16) u16 tmp[16];
            #pragma unroll
            for (int q = 0; q < 16; ++q) stbf(&tmp[q], src[q]);
            *(int4*)&smB[srow * 32 + scol]     = *(const int4*)&tmp[0];
            *(int4*)&smB[srow * 32 + scol + 8] = *(const int4*)&tmp[8];
        }
        __syncthreads();

        bf16x8 af[4], bfr[4];
        #pragma unroll
        for (int mi = 0; mi < 4; ++mi)
            af[mi] = *(const bf16x8*)&smA[(wm * 64 + mi * 16 + (lane & 15)) * 32 + (lane >> 4) * 8];
        #pragma unroll
        for (int ni = 0; ni < 4; ++ni)
            bfr[ni] = *(const bf16x8*)&smB[(wn * 64 + ni * 16 + (lane & 15)) * 32 + (lane >> 4) * 8];
        #pragma unroll
        for (int mi = 0; mi < 4; ++mi)
            #pragma unroll
            for (int ni = 0; ni < 4; ++ni)
                acc[mi][ni] = __builtin_amdgcn_mfma_f32_16x16x32_bf16(af[mi], bfr[ni], acc[mi][ni], 0, 0, 0);
        __syncthreads();
    }

    // epilogue: C/D layout col = lane&15, row = (lane>>4)*4 + r
    u16* gt = gates + (size_t)blockIdx.x * 262144;
    #pragma unroll
    for (int ni = 0; ni < 4; ++ni) {
        const int n = (int)nbase + wn * 64 + ni * 16 + (lane & 15);
        const float bias = bih[n] + bhh[n];
        const int g  = n >> 9;
        const int jh = n & 511;
        u16* gb = gt + (size_t)(jh >> 4) * 8192 + (size_t)(g * 16 + (jh & 15));
        #pragma unroll
        for (int mi = 0; mi < 4; ++mi) {
            const int b = wm * 64 + mi * 16 + (lane >> 4) * 4;
            #pragma unroll
            for (int r = 0; r < 4; ++r)
                stbf(gb + (size_t)(b + r) * 64, acc[mi][ni][r] + bias);
        }
    }
}

// ---------------------------------------------------------------------------
// Persistent LSTM, round 5 (round-3 structure + three safe changes).
// Round-3 residual: ~9600cy/step with all pipes idle; model says the serial
// L3 chain is ~4000cy, so the rest is contention at the single barrier
// counter (32 RMW arrivals + continuous polls on ONE cacheline serialize at
// the coherence point). Changes:
//  1. flag-array barrier: arrival = one agent-scope atomic STORE per block
//     to its own 256B-spaced flag (no RMW); wait = wave0's 32 lanes poll all
//     32 flags in parallel (own slot pre-done).
//  2. w_hh MFMA fragments hoisted to registers once (64 VGPR/wave): no smW
//     reads in the loop.
//  3. tanh_fast instead of library tanhf in the elementwise step.
// ---------------------------------------------------------------------------
__global__ __launch_bounds__(256) void lstm_persist(const u16* __restrict__ gates,
                                                    const u16* __restrict__ whh,
                                                    u16* __restrict__ hbuf,
                                                    float* __restrict__ out,
                                                    unsigned* __restrict__ flags) {
    __shared__ __align__(16) u16 smW[32768];   // [64 n][512 k] swizzled (64 KB)
    __shared__ __align__(16) u16 smH[16384];   // [32 b][512 k] swizzled (32 KB)
    __shared__ __align__(16) float smG[4 * 32 * 18];  // pad 16->18

    const int tid  = threadIdx.x;
    const int lane = tid & 63;
    const int wave = tid >> 6;                 // gate group i,f,g,o
    const int bid  = blockIdx.x;
    const int grp  = bid >> 5;                 // batch group
    const int jt   = bid & 31;                 // hidden-col tile
    const int b0   = grp << 5;
    const int jh0  = jt << 4;
    unsigned* myflag = flags + grp * 2048 + jt * 64;   // 256 B apart

    // ---- stage w_hh slice once ----
    for (int i = tid; i < 4096; i += 256) {
        const int row = i >> 6;                // 0..63
        const int c8  = i & 63;                // 16B chunk within row
        const u16* src = whh + ((size_t)((row >> 4) * 512 + jh0 + (row & 15))) * 512 + c8 * 8;
        int4 v = *(const int4*)src;
        int byte = row * 1024 + c8 * 16;
        byte ^= (row & 7) << 4;
        *(int4*)((char*)smW + byte) = v;
    }

    const int fr = lane & 15;                  // fragment row-in-tile
    const int kq = lane >> 4;                  // k quad
    const int br = tid >> 3;                   // elementwise batch row 0..31
    const int j2 = (tid & 7) * 2;              // elementwise col pair
    float cA = 0.0f, cB = 0.0f;                // c-state in registers (j2, j2+1)

    __syncthreads();

    // ---- hoist w_hh fragments into registers (constant across all steps) ----
    const int brow = wave * 16 + fr;
    const int bxor = (brow & 7) << 4;
    const int axor = (fr & 7) << 4;
    bf16x8 wfrag[16];
    #pragma unroll
    for (int kt = 0; kt < 16; ++kt)
        wfrag[kt] = *(const bf16x8*)((const char*)smW + ((brow * 1024 + kt * 64 + kq * 16) ^ bxor));

    for (int t = 0; t < 511; ++t) {
        // ---- stage h tile [32][512] bf16: batch-issue 16 coherent loads ----
        const u64* hp = (const u64*)(hbuf + (size_t)(t & 1) * 65536 + (size_t)b0 * 512);
        u64 tmp[16];
        #pragma unroll
        for (int i = 0; i < 16; ++i)
            tmp[i] = __hip_atomic_load(hp + i * 256 + tid,
                                       __ATOMIC_RELAXED, __HIP_MEMORY_SCOPE_AGENT);
        __builtin_amdgcn_sched_barrier(0);     // keep LDS writes below the loads
        #pragma unroll
        for (int i = 0; i < 16; ++i) {
            const int e   = i * 256 + tid;
            const int row = e >> 7;            // 0..31
            const int c4  = e & 127;           // 8B chunk within row
            const int byte = (row * 1024 + c4 * 8) ^ ((row & 7) << 4);
            *(u64*)((char*)smH + byte) = tmp[i];
        }
        // ---- prefetch gx (independent; hides under MFMA) ----
        const u16* gsrc = gates + (size_t)t * 262144 + (size_t)jt * 8192 + (size_t)b0 * 64;
        unsigned gx4[4];
        #pragma unroll
        for (int g = 0; g < 4; ++g)
            gx4[g] = *(const unsigned*)(gsrc + br * 64 + g * 16 + j2);

        __syncthreads();

        // ---- gates GEMM: wave g computes [32 b][16 j] of gate g, K=512 ----
        f32x4 acc0 = {}, acc1 = {};
        #pragma unroll
        for (int kt = 0; kt < 16; ++kt) {
            const int kb = kt * 64 + kq * 16;
            bf16x8 a0 = *(const bf16x8*)((const char*)smH + ((fr * 1024 + kb) ^ axor));
            bf16x8 a1 = *(const bf16x8*)((const char*)smH + (((16 + fr) * 1024 + kb) ^ axor));
            acc0 = __builtin_amdgcn_mfma_f32_16x16x32_bf16(a0, wfrag[kt], acc0, 0, 0, 0);
            acc1 = __builtin_amdgcn_mfma_f32_16x16x32_bf16(a1, wfrag[kt], acc1, 0, 0, 0);
        }

        // ---- dump gates to LDS: m = kq*4+r, n = fr (row pad 18 floats) ----
        #pragma unroll
        for (int r = 0; r < 4; ++r) {
            smG[(wave * 32 + kq * 4 + r) * 18 + fr]      = acc0[r];
            smG[(wave * 32 + 16 + kq * 4 + r) * 18 + fr] = acc1[r];
        }
        __syncthreads();

        // ---- elementwise LSTM: thread owns (br, j2) and (br, j2+1) ----
        u16*   hdst = hbuf + (size_t)((t + 1) & 1) * 65536;
        float* odst = out + ((size_t)t * 128 + b0 + br) * 512 + jh0;
        float hn0, hn1;
        {
            const float gi = smG[(0 * 32 + br) * 18 + j2] + bf2f((u16)(gx4[0] & 0xffff));
            const float gf = smG[(1 * 32 + br) * 18 + j2] + bf2f((u16)(gx4[1] & 0xffff));
            const float gg = smG[(2 * 32 + br) * 18 + j2] + bf2f((u16)(gx4[2] & 0xffff));
            const float go = smG[(3 * 32 + br) * 18 + j2] + bf2f((u16)(gx4[3] & 0xffff));
            cA = sigm(gf) * cA + sigm(gi) * tanh_fast(gg);
            hn0 = sigm(go) * tanh_fast(cA);
        }
        {
            const float gi = smG[(0 * 32 + br) * 18 + j2 + 1] + bf2f((u16)(gx4[0] >> 16));
            const float gf = smG[(1 * 32 + br) * 18 + j2 + 1] + bf2f((u16)(gx4[1] >> 16));
            const float gg = smG[(2 * 32 + br) * 18 + j2 + 1] + bf2f((u16)(gx4[2] >> 16));
            const float go = smG[(3 * 32 + br) * 18 + j2 + 1] + bf2f((u16)(gx4[3] >> 16));
            cB = sigm(gf) * cB + sigm(gi) * tanh_fast(gg);
            hn1 = sigm(go) * tanh_fast(cB);
        }
        // h store: packed u32, coherent (bypasses local L2, lands at L3)
        {
            const unsigned hw = (unsigned)f2bfu(hn0) | ((unsigned)f2bfu(hn1) << 16);
            __hip_atomic_store((unsigned*)(hdst + (size_t)(b0 + br) * 512 + jh0 + j2),
                               hw, __ATOMIC_RELAXED, __HIP_MEMORY_SCOPE_AGENT);
        }
        // out store: plain cached f32 (visibility at kernel end)
        *(float2*)(odst + j2) = make_float2(hn0, hn1);

        // ---- flag-array barrier: store own flag, poll 32 flags in parallel ----
        if (t < 510) {
            asm volatile("s_waitcnt vmcnt(0)" ::: "memory");  // own h stores ack'd
            __syncthreads();                                  // whole block ack'd
            if (tid == 0)
                __hip_atomic_store(myflag, (unsigned)(t + 1),
                                   __ATOMIC_RELAXED, __HIP_MEMORY_SCOPE_AGENT);
            if (wave == 0) {
                const unsigned tgt = (unsigned)(t + 1);
                unsigned* fp = flags + grp * 2048 + lane * 64;
                int done = (lane >= 32 || lane == jt) ? 1 : 0;  // own slot pre-done
                while (!__all(done)) {
                    if (!done)
                        done = (__hip_atomic_load(fp, __ATOMIC_RELAXED,
                                                  __HIP_MEMORY_SCOPE_AGENT) >= tgt);
                }
            }
            __syncthreads();
            asm volatile("" ::: "memory");
        }
    }
}

// ---------------------------------------------------------------------------
extern "C" void kernel_launch(void* const* d_in, const int* in_sizes, int n_in,
                              void* d_out, int out_size, void* d_ws, size_t ws_size,
                              hipStream_t stream) {
    const float* x   = (const float*)d_in[0];
    const float* z   = (const float*)d_in[1];
    const float* c0w = (const float*)d_in[2];
    const float* c0b = (const float*)d_in[3];
    const float* c1w = (const float*)d_in[4];
    const float* c1b = (const float*)d_in[5];
    const float* wih = (const float*)d_in[6];
    const float* whh = (const float*)d_in[7];
    const float* bih = (const float*)d_in[8];
    const float* bhh = (const float*)d_in[9];
    float* out = (float*)d_out;                // f32 output (reference dtype)
    char* ws = (char*)d_ws;

    // workspace layout (bytes) — total 371,195,904 (unchanged)
    u16*      z1     = (u16*)(ws);              //  33,554,432 B: [256][128][512] bf16
    u16*      z2     = (u16*)(ws + 33554432);   //  67,108,864 B: [512][128][512] bf16
    u16*      gates  = (u16*)(ws + 100663296);  // 267,911,168 B: [511][32][128][4][16] bf16
    unsigned* flags  = (unsigned*)(ws + 368574464); // 4 grp x 32 slots x 256 B = 32 KB
    u16*      hbuf   = (u16*)(ws + 368836608);  //     262,144 B: [2][128][512] bf16
    u16*      whh_bf = (u16*)(ws + 369098752);  //   2,097,152 B: [2048][512] bf16

    hipMemsetAsync(flags, 0, 32768, stream);
    hipMemsetAsync(hbuf, 0, 131072, stream);    // zero h[0] buffer only

    // convert w_hh to bf16
    cvt_bf16<<<dim3(4096), 256, 0, stream>>>(whh, whh_bf, 1048576);

    // upsample x2
    upsample<true ><<<dim3(16777216 / 256), 256, 0, stream>>>(z,  c0w, c0b, z1, 128, 2);
    upsample<false><<<dim3(33554432 / 256), 256, 0, stream>>>(z1, c1w, c1b, z2, 256, 1);

    // gates_x = [x[:-1] | z2[1:]] @ w_ih^T + b_ih + b_hh  (tiled layout)
    gemm_gates<<<dim3(511, 16), 256, 0, stream>>>(x, z2, wih, bih, bhh, gates);

    // whole recurrence in one cooperative persistent kernel
    {
        const u16* gates_a = gates;
        const u16* whh_a   = whh_bf;
        u16*       hbuf_a  = hbuf;
        float*     out_a   = out;
        unsigned*  flags_a = flags;
        void* args[] = {&gates_a, &whh_a, &hbuf_a, &out_a, &flags_a};
        hipLaunchCooperativeKernel((void*)lstm_persist, dim3(128), dim3(256),
                                   args, 0, stream);
    }
}